// Round 9
// baseline (73.163 us; speedup 1.0000x reference)
//
// InputLayer Rayleigh-Sommerfeld — round 9: Toeplitz-decomposed MFMA GEMM
// Out[di][dj] = sum_a sum_sj W[a][dj-sj+95] * Z_a[di][sj],  Z_a = x[di-a]+x[di+a]
#include <hip/hip_runtime.h>

namespace rs9 {

constexpr int kN   = 96;
constexpr int kN2  = kN * kN;              // 9216
constexpr int kSlab = 2 * kN2;             // floats per slab (re+im planes)
constexpr float kScale   = 1.0f / 65536.0f;
constexpr float kUnscale = 65536.0f;

typedef _Float16 f16x8 __attribute__((ext_vector_type(8)));
typedef _Float16 f16x2 __attribute__((ext_vector_type(2)));
typedef float    f32x4 __attribute__((ext_vector_type(4)));

// LDS layout: ZS 96 rows x 104 halves (bank-pad) | 8 shifted copies x 200 halves x 2 planes
constexpr int kZRow   = 104;                       // halves per Z row (padded)
constexpr int kZBytes = kN * kZRow * 2;            // 19968
constexpr int kCopyH  = 200;                       // halves per shifted copy (400 B)
constexpr int kWBytes = 8 * kCopyH * 2;            // 3200 per plane

__global__ __launch_bounds__(256) void rs_gemm_v9(const float* __restrict__ img,
                                                  float* __restrict__ ws) {
    const float dl      = (float)(1e-3 / 96.0);
    const float dz      = 0.01f;
    const float dz2     = dz * dz;
    const float lam_amp = (float)(1.0 / 1.55e-6);
    const float inv_2pi = 1.0f / 6.2831855f;
    const float k32     = 6.2831855f / 1.55e-6f;   // fp32(2pi)/fp32(lambda)

    __shared__ __align__(16) unsigned char lds[kZBytes + 2 * kWBytes];
    _Float16* ZS  = (_Float16*)lds;
    _Float16* WRe = (_Float16*)(lds + kZBytes);
    _Float16* WIm = (_Float16*)(lds + kZBytes + kWBytes);

    const int a   = (int)blockIdx.x;               // row offset |di-si|
    const int tid = (int)threadIdx.x;

    // ---- 1) table row W[a][c], c=0..190; write 8 shift-replicated reversed copies ----
    if (tid < 191) {
        const float ax = (float)a * dl;
        const float by = (float)(tid - 95) * dl;
        const float r  = sqrtf(ax * ax + by * by + dz2);
        const float theta = k32 * r;               // fp32-rounded phase (as reference)
        const float sn = sinf(theta);
        const float cs = cosf(theta);
        const float rinv = 1.0f / r;
        const float ampf = dz * rinv * rinv;
        const float nearf = rinv * inv_2pi;
        const _Float16 hre = (_Float16)(ampf * (nearf * cs + lam_amp * sn) * kScale);
        const _Float16 him = (_Float16)(ampf * (nearf * sn - lam_amp * cs) * kScale);
        const int cp = 190 - tid;                  // reversed index: WR[cp] = W[c]
#pragma unroll
        for (int s = 0; s < 8; ++s) {
            const int q = cp - s;                  // copy s holds WR[q+s] at q
            if (q >= 0) {
                WRe[s * kCopyH + q] = hre;
                WIm[s * kCopyH + q] = him;
            }
        }
    }

    // ---- 2) Z_a rows in fp16 (padded to 104 halves) ----
    for (int idx = tid; idx < kN * 48; idx += 256) {
        const int m  = idx / 48;                   // di
        const int c2 = idx - m * 48;               // half2 column
        float vx = 0.0f, vy = 0.0f;
        const int r1 = m - a, r2 = m + a;
        if (r1 >= 0) {
            const float2 t = ((const float2*)(img + r1 * kN))[c2];
            vx += t.x; vy += t.y;
        }
        if (a > 0 && r2 < kN) {
            const float2 t = ((const float2*)(img + r2 * kN))[c2];
            vx += t.x; vy += t.y;
        }
        f16x2 h; h.x = (_Float16)vx; h.y = (_Float16)vy;
        *(f16x2*)(ZS + m * kZRow + c2 * 2) = h;
    }
    __syncthreads();

    // ---- 3) MFMA: wave (wr,wc) owns 3x3 tiles of the 6x6 out grid ----
    const int lane = tid & 63, wid = tid >> 6;
    const int quad = lane >> 4, l15 = lane & 15;
    const int wr = wid >> 1, wc = wid & 1;

    const f32x4 vzero = {0.0f, 0.0f, 0.0f, 0.0f};
    f32x4 acc[3][3][2];
#pragma unroll
    for (int mi = 0; mi < 3; ++mi)
#pragma unroll
        for (int ni = 0; ni < 3; ++ni) { acc[mi][ni][0] = vzero; acc[mi][ni][1] = vzero; }

    for (int kt = 0; kt < 3; ++kt) {
        const int k0 = kt * 32 + quad * 8;         // k base for this lane's regs
        f16x8 afrag[3];
#pragma unroll
        for (int mi = 0; mi < 3; ++mi) {
            const int m = (wr * 3 + mi) * 16 + l15;        // A[m][k0..k0+7]
            afrag[mi] = *(const f16x8*)(ZS + m * kZRow + k0);
        }
#pragma unroll
        for (int ni = 0; ni < 3; ++ni) {
            const int n = (wc * 3 + ni) * 16 + l15;        // B[k][n] = W[n-k+95]
            const int p = 95 + k0 - n;                     // reversed-table start index
            const int s = p & 7;                           // shifted-copy select
            const int off = s * kCopyH + (p - s);          // 16B-aligned
            const f16x8 bre = *(const f16x8*)(WRe + off);
            const f16x8 bim = *(const f16x8*)(WIm + off);
#pragma unroll
            for (int mi = 0; mi < 3; ++mi) {
                acc[mi][ni][0] = __builtin_amdgcn_mfma_f32_16x16x32_f16(afrag[mi], bre, acc[mi][ni][0], 0, 0, 0);
                acc[mi][ni][1] = __builtin_amdgcn_mfma_f32_16x16x32_f16(afrag[mi], bim, acc[mi][ni][1], 0, 0, 0);
            }
        }
    }

    // ---- 4) write this a's partial Out to its slab (fully overwritten, no init) ----
    float* slab = ws + (size_t)a * kSlab;
#pragma unroll
    for (int mi = 0; mi < 3; ++mi) {
#pragma unroll
        for (int ni = 0; ni < 3; ++ni) {
            const int dj = (wc * 3 + ni) * 16 + l15;
#pragma unroll
            for (int rg = 0; rg < 4; ++rg) {
                const int di = (wr * 3 + mi) * 16 + quad * 4 + rg;  // C/D row = quad*4+reg
                slab[di * kN + dj]       = acc[mi][ni][0][rg];
                slab[kN2 + di * kN + dj] = acc[mi][ni][1][rg];
            }
        }
    }
}

__global__ __launch_bounds__(256) void rs_reduce_v9(const float* __restrict__ img,
                                                    const float* __restrict__ ws,
                                                    float* __restrict__ out) {
    const int tid = (int)threadIdx.x;
    const int g   = (int)blockIdx.x * 256 + tid;   // 0..18431

    float vmax = 0.0f;
    for (int t = tid; t < kN2; t += 256) vmax = fmaxf(vmax, img[t]);
    for (int off = 32; off >= 1; off >>= 1) vmax = fmaxf(vmax, __shfl_xor(vmax, off, 64));
    __shared__ float smax[4];
    if ((tid & 63) == 0) smax[tid >> 6] = vmax;
    __syncthreads();
    const float gmax  = fmaxf(fmaxf(smax[0], smax[1]), fmaxf(smax[2], smax[3]));
    const float scale = kUnscale / gmax;           // undo fp16 W scaling + 1/max

    float s0 = 0.0f, s1 = 0.0f, s2 = 0.0f, s3 = 0.0f;
#pragma unroll
    for (int s = 0; s < kN; s += 4) {
        s0 += ws[(size_t)(s + 0) * kSlab + g];
        s1 += ws[(size_t)(s + 1) * kSlab + g];
        s2 += ws[(size_t)(s + 2) * kSlab + g];
        s3 += ws[(size_t)(s + 3) * kSlab + g];
    }
    out[g] = ((s0 + s1) + (s2 + s3)) * scale;
}

}  // namespace rs9

extern "C" void kernel_launch(void* const* d_in, const int* in_sizes, int n_in,
                              void* d_out, int out_size, void* d_ws, size_t ws_size,
                              hipStream_t stream) {
    (void)in_sizes; (void)n_in; (void)out_size; (void)ws_size;
    const float* img = (const float*)d_in[0];
    float* ws  = (float*)d_ws;
    float* out = (float*)d_out;
    hipLaunchKernelGGL(rs9::rs_gemm_v9, dim3(rs9::kN), dim3(256), 0, stream, img, ws);
    hipLaunchKernelGGL(rs9::rs_reduce_v9, dim3(2 * rs9::kN2 / 256), dim3(256), 0, stream,
                       img, ws, out);
}